// Round 7
// baseline (109.793 us; speedup 1.0000x reference)
//
#include <hip/hip_runtime.h>

typedef unsigned long long u64;
typedef unsigned int u32;

#define NBOX 8192
#define NW64 128    // u64 words per fallback suppression bitmap
#define NCLASS 80
#define MAXC 512    // clist capacity per class
#define NCMAX 256   // fast-path class size cap (nc>256 is ~9 sigma -> fallback)
#define CHKCAP 256
#define NS 8        // rank slices
#define SLICE 1024  // NBOX / NS
#define NBLKS 256   // grid size; small footprint -> all blocks co-resident

// ---- monotone float<->uint mapping (order-preserving for all floats) ----
__device__ __forceinline__ u32 f32_mono(float f) {
  u32 u = __float_as_uint(f);
  return (u & 0x80000000u) ? ~u : (u | 0x80000000u);
}
__device__ __forceinline__ float mono_f32(u32 u) {
  u32 b = (u & 0x80000000u) ? (u ^ 0x80000000u) : ~u;
  return __uint_as_float(b);
}
__device__ __forceinline__ float readlane_f(float v, int l) {
  return __uint_as_float(__builtin_amdgcn_readlane(__float_as_uint(v), l));
}
// reduce 32-entry u32 array of block maxima, in-register
__device__ __forceinline__ u32 reduce_bmax(const u32* __restrict__ bmax, int t) {
  u32 bm = bmax[t & 31];
#pragma unroll
  for (int off = 16; off > 0; off >>= 1) {
    u32 o = __shfl_xor(bm, off);
    bm = (bm > o) ? bm : o;
  }
  return bm;
}

// ---- ticket-based grid barrier. Works from any multiple-of-256 start value
// (memset node zeroes it each replay). __threadfence() (agent scope) emits
// buffer_wbl2 / buffer_inv on gfx950 -> plain stores become visible across
// XCD L2s, same guarantee the inter-kernel boundary used to provide.
__device__ __forceinline__ void gbar(u32* bar) {
  __syncthreads();
  if (threadIdx.x == 0) {
    __threadfence();  // release: drain + writeback L2
    u32 ticket = atomicAdd(bar, 1u);
    u32 target = (ticket & ~255u) + 256u;
    while ((int)(atomicAdd(bar, 0u) - target) < 0) {
      __builtin_amdgcn_s_sleep(4);
    }
    __threadfence();  // acquire: invalidate L1/L2
  }
  __syncthreads();
}

__global__ __launch_bounds__(256) void mega_kernel(
    const float* __restrict__ scores, const int* __restrict__ class_ids,
    const float4* __restrict__ deltas, const float2* __restrict__ locs,
    const int* __restrict__ stride_p,
    float4* __restrict__ boxes_out, float* __restrict__ keep_out,
    float* __restrict__ order_out,
    u32* bar, u32* __restrict__ bmax, int* flag, int* __restrict__ ccount,
    int* __restrict__ rankp, int* __restrict__ rcp,
    u64* __restrict__ keys, float4* __restrict__ bnms,
    u32* __restrict__ clist) {
  const int t = threadIdx.x;
  const int bid = blockIdx.x;
  const int b = bid & 31;       // i-range selector
  const int slice = bid >> 5;   // 0..7 (j-slice)
  const int i = b * 256 + t;

  __shared__ u64 kt[SLICE];
  __shared__ u32 wmax[4];
  __shared__ float4 bxA[CHKCAP], bxB[CHKCAP];
  __shared__ int clsA[CHKCAP], clsB[CHKCAP];
  __shared__ int na, nb;
  __shared__ u64 remv[NW64];

  // ================= phase A: rank partials + decode + init =================
  const u32 mi = f32_mono(scores[i]);
  const int ci = class_ids[i];
  float4 bdec = {0.f, 0.f, 0.f, 0.f};

  if (slice == 0) {  // blocks 0..31: decode boxes + per-wave max
    float s = (float)(*stride_p);
    float4 d = deltas[i];
    d.x = fmaxf(d.x, 0.f); d.y = fmaxf(d.y, 0.f);
    d.z = fmaxf(d.z, 0.f); d.w = fmaxf(d.w, 0.f);
    float2 c = locs[i];
    bdec.x = c.x - s * d.x;
    bdec.y = c.y - s * d.y;
    bdec.z = c.x + s * d.z;
    bdec.w = c.y + s * d.w;
    boxes_out[i] = bdec;
    float m = fmaxf(fmaxf(bdec.x, bdec.y), fmaxf(bdec.z, bdec.w));
    u32 u = f32_mono(m);
#pragma unroll
    for (int off = 32; off > 0; off >>= 1) {
      u32 o = __shfl_xor(u, off);
      u = (u > o) ? u : o;
    }
    if ((t & 63) == 0) wmax[t >> 6] = u;
  }
  if (bid == 0) {  // init flag/ccount (visible after gbar)
    if (t == 0) *flag = 0;
    if (t < NCLASS) ccount[t] = 0;
  }

  for (int p = t; p < SLICE; p += 256) {
    int j = slice * SLICE + p;
    u32 mj = f32_mono(scores[j]);
    kt[p] = ((u64)(~mj) << 32) | ((u32)j << 8) | (u32)(class_ids[j] & 0xff);
  }
  __syncthreads();
  if (slice == 0 && t == 0) {
    u32 m0 = wmax[0] > wmax[1] ? wmax[0] : wmax[1];
    u32 m1 = wmax[2] > wmax[3] ? wmax[2] : wmax[3];
    bmax[b] = m0 > m1 ? m0 : m1;
  }

  {
    u64 ki = ((u64)(~mi) << 32) | ((u32)i << 8) | (u32)(ci & 0xff);
    int cnt = 0, ccnt = 0;
#pragma unroll 8
    for (int p = 0; p < SLICE; ++p) {
      u64 kj = kt[p];  // wave-uniform LDS address -> broadcast
      bool less = kj < ki;
      bool ceq = (((u32)(kj ^ ki)) & 0xffu) == 0u;
      cnt += less ? 1 : 0;
      ccnt += (less && ceq) ? 1 : 0;
    }
    rankp[slice * NBOX + i] = cnt;
    rcp[slice * NBOX + i] = ccnt;
  }

  gbar(bar);

  // ================= phase C: scatter by rank (blocks 0..31) ================
  if (slice == 0) {
    int r = 0, rc = 0;
#pragma unroll
    for (int s = 0; s < NS; ++s) {
      r += rankp[s * NBOX + i];
      rc += rcp[s * NBOX + i];
    }
    float maxc = mono_f32(reduce_bmax(bmax, t));
    keys[r] = ((u64)(~mi) << 32) | (u32)i;  // clean key for fallback
    float off = (float)ci * (maxc + 1.0f);
    float4 bb = bdec;
    bb.x += off; bb.y += off; bb.z += off; bb.w += off;
    bnms[r] = bb;
    order_out[r] = (float)i;
    if (rc < MAXC)
      clist[ci * MAXC + rc] = ((u32)i << 16) | (u32)r;
    else
      atomicOr(flag, 1);  // class overflow -> exact fallback
    atomicAdd(&ccount[ci], 1);
  }

  gbar(bar);

  // ========== phase E: per-class NMS (0..79) + hazard check (80) ===========
  if (bid == NCLASS) {
    // Cross-class hazard: adjacent-class offset boxes can only overlap if one
    // box hugs the top-right margin (x2,y2 > M-65; x1,y1 >= -64 by
    // construction) and the other the bottom-left margin (x1,y1 < 1).
    // Conservative IoU > 0.4 vs reference 0.5.
    if (t == 0) { na = 0; nb = 0; }
    __syncthreads();
    float M = mono_f32(reduce_bmax(bmax, t));
    float thrA = M - 65.0f;
    for (int base = 0; base < NBOX; base += 256) {
      int ii = base + t;
      float4 bb = boxes_out[ii];
      int cls = class_ids[ii];
      if (bb.z > thrA && bb.w > thrA) {
        int p = atomicAdd(&na, 1);
        if (p < CHKCAP) { bxA[p] = bb; clsA[p] = cls; }
      }
      if (bb.x < 1.0f && bb.y < 1.0f) {
        int p = atomicAdd(&nb, 1);
        if (p < CHKCAP) { bxB[p] = bb; clsB[p] = cls; }
      }
    }
    __syncthreads();
    int NA = na < CHKCAP ? na : CHKCAP;
    int NB = nb < CHKCAP ? nb : CHKCAP;
    if (t == 0 && (na > CHKCAP || nb > CHKCAP)) atomicOr(flag, 1);
    bool hit = false;
    for (int pr = t; pr < NA * NB; pr += 256) {
      int a = pr / NB, b2 = pr % NB;
      if (clsB[b2] != clsA[a] + 1) continue;
      float offa = (float)clsA[a] * (M + 1.0f);
      float offb = (float)clsB[b2] * (M + 1.0f);
      float4 A = bxA[a], Bb = bxB[b2];
      A.x += offa; A.y += offa; A.z += offa; A.w += offa;
      Bb.x += offb; Bb.y += offb; Bb.z += offb; Bb.w += offb;
      float ltx = fmaxf(A.x, Bb.x), lty = fmaxf(A.y, Bb.y);
      float rbx = fminf(A.z, Bb.z), rby = fminf(A.w, Bb.w);
      float ww = fmaxf(rbx - ltx, 0.f), hh = fmaxf(rby - lty, 0.f);
      float inter = ww * hh;
      float aa = (A.z - A.x) * (A.w - A.y);
      float ab = (Bb.z - Bb.x) * (Bb.w - Bb.y);
      float iou = inter / (aa + ab - inter);
      if (iou > 0.4f) hit = true;
    }
    if (hit) atomicOr(flag, 1);
  } else if (bid < NCLASS && t < 64) {
    // all-register greedy NMS: lane t owns boxes t, t+64, t+128, t+192;
    // remv lives as 4 wave-uniform u64. Per kept row: 4 readlanes broadcast
    // box i, <=4 IoU+ballot passes OR into remv. No LDS on the serial path.
    int c = bid;
    int nc = ccount[c];
    if (nc > NCMAX) {
      if (t == 0) atomicOr(flag, 1);
    } else {
      u32 L[4];
      float4 B[4];
#pragma unroll
      for (int d = 0; d < 4; ++d) {
        int j = d * 64 + t;
        L[d] = (j < nc) ? clist[c * MAXC + j] : 0u;
        B[d] = bnms[L[d] & 0xffffu];  // j>=nc -> harmless read of bnms[0]
      }
      u64 r0 = 0, r1 = 0, r2 = 0, r3 = 0;

#define CHUNK(CC, RC, PASSES)                                                  \
  {                                                                            \
    int lim = nc - CC * 64;                                                    \
    if (lim > 0) {                                                             \
      if (lim > 64) lim = 64;                                                  \
      for (int ii = 0; ii < lim; ++ii) {                                       \
        if (!((RC >> ii) & 1ull)) {                                            \
          float bix = readlane_f(B[CC].x, ii);                                 \
          float biy = readlane_f(B[CC].y, ii);                                 \
          float biz = readlane_f(B[CC].z, ii);                                 \
          float biw = readlane_f(B[CC].w, ii);                                 \
          float area_i = (biz - bix) * (biw - biy);                            \
          PASSES                                                               \
        }                                                                      \
      }                                                                        \
    }                                                                          \
  }
#define PASS(DD, RD, JGUARD)                                                   \
  {                                                                            \
    float4 bj = B[DD];                                                         \
    float ltx = fmaxf(bix, bj.x), lty = fmaxf(biy, bj.y);                      \
    float rbx = fminf(biz, bj.z), rby = fminf(biw, bj.w);                      \
    float ww = fmaxf(rbx - ltx, 0.f), hh = fmaxf(rby - lty, 0.f);              \
    float inter = ww * hh;                                                     \
    float area_j = (bj.z - bj.x) * (bj.w - bj.y);                              \
    float iou = inter / (area_i + area_j - inter);                             \
    int j = DD * 64 + t;                                                       \
    bool p = (iou > 0.5f) && (j < nc) && (JGUARD);                             \
    RD |= __ballot(p);                                                         \
  }

      CHUNK(0, r0, PASS(0, r0, t > ii) PASS(1, r1, true) PASS(2, r2, true) PASS(3, r3, true))
      CHUNK(1, r1, PASS(1, r1, t > ii) PASS(2, r2, true) PASS(3, r3, true))
      CHUNK(2, r2, PASS(2, r2, t > ii) PASS(3, r3, true))
      CHUNK(3, r3, PASS(3, r3, t > ii))
#undef PASS
#undef CHUNK

      u64 rr[4] = {r0, r1, r2, r3};
#pragma unroll
      for (int d = 0; d < 4; ++d) {
        int j = d * 64 + t;
        if (j < nc) keep_out[L[d] >> 16] = ((rr[d] >> t) & 1ull) ? 0.0f : 1.0f;
      }
    }
  }

  gbar(bar);

  // ===== phase G: exact single-block fallback (only if flag != 0) ==========
  if (bid == 0) {
    if (*flag != 0) {
      for (int k = t; k < NW64; k += 256) remv[k] = 0;
      __syncthreads();
      if (t < 64) {
        int lane = t;
        for (int ii = 0; ii < NBOX; ++ii) {
          if ((remv[ii >> 6] >> (ii & 63)) & 1ull) continue;
          float4 bi = bnms[ii];
          float area_i = (bi.z - bi.x) * (bi.w - bi.y);
          for (int jb = ii + 1; jb < NBOX; jb += 64) {
            int j = jb + lane;
            bool p = false;
            if (j < NBOX) {
              float4 bj = bnms[j];
              float ltx = fmaxf(bi.x, bj.x), lty = fmaxf(bi.y, bj.y);
              float rbx = fminf(bi.z, bj.z), rby = fminf(bi.w, bj.w);
              float ww = fmaxf(rbx - ltx, 0.f), hh = fmaxf(rby - lty, 0.f);
              float inter = ww * hh;
              float area_j = (bj.z - bj.x) * (bj.w - bj.y);
              float iou = inter / (area_i + area_j - inter);
              p = iou > 0.5f;
            }
            u64 m = __ballot(p);
            if (lane == 0 && m) {
              int w0 = jb >> 6, sh = jb & 63;
              remv[w0] |= (m << sh);
              if (sh && (w0 + 1) < NW64) remv[w0 + 1] |= (m >> (64 - sh));
            }
          }
        }
      }
      __syncthreads();
      for (int k = t; k < NBOX; k += 256)
        keep_out[(u32)keys[k]] = ((remv[k >> 6] >> (k & 63)) & 1ull) ? 0.0f : 1.0f;
    }
  }
}

extern "C" void kernel_launch(void* const* d_in, const int* in_sizes, int n_in,
                              void* d_out, int out_size, void* d_ws, size_t ws_size,
                              hipStream_t stream) {
  const float* deltas = (const float*)d_in[0];
  const float* locs = (const float*)d_in[1];
  const float* scores = (const float*)d_in[2];
  const int* class_ids = (const int*)d_in[3];
  const int* stride_p = (const int*)d_in[4];
  int n = in_sizes[2];  // 8192
  (void)n;

  float* boxes_out = (float*)d_out;                  // n*4 floats
  float* keep_out = (float*)d_out + (size_t)NBOX * 4;   // n floats (0/1)
  float* order_out = (float*)d_out + (size_t)NBOX * 5;  // n floats (indices)

  // workspace layout
  u32* bar = (u32*)d_ws;                          // @0, barrier ticket (zeroed)
  u32* bmax = (u32*)((char*)d_ws + 64);           // 32*4 B, plain-stored
  int* flag = (int*)((char*)d_ws + 256);          // init'd in-kernel
  int* ccount = (int*)((char*)d_ws + 512);        // 80*4 B, init'd in-kernel
  u64* keys = (u64*)((char*)d_ws + 4096);         // 64 KiB
  float4* bnms = (float4*)((char*)d_ws + 4096 + 65536);  // 128 KiB
  char* base2 = (char*)d_ws + 4096 + 65536 + 131072;
  int* rankp = (int*)base2;                       // NS*8192*4 = 256 KiB
  int* rcp = (int*)(base2 + 256 * 1024);          // 256 KiB
  u32* clist = (u32*)(base2 + 512 * 1024);        // 80*512*4 = 160 KiB

  hipMemsetAsync(d_ws, 0, 64, stream);  // reset barrier ticket each replay

  mega_kernel<<<NBLKS, 256, 0, stream>>>(
      scores, class_ids, (const float4*)deltas, (const float2*)locs, stride_p,
      (float4*)boxes_out, keep_out, order_out,
      bar, bmax, flag, ccount, rankp, rcp, keys, bnms, clist);
}

// Round 8
// 71.649 us; speedup vs baseline: 1.5324x; 1.5324x over previous
//
#include <hip/hip_runtime.h>

typedef unsigned long long u64;
typedef unsigned int u32;

#define NBOX 8192
#define NW64 128    // u64 words per fallback suppression bitmap
#define NCLASS 80
#define MAXC 512    // clist capacity per class
#define NCMAX 256   // fast-path class size cap (nc>256 is ~9 sigma -> fallback)
#define CHKCAP 256
#define NS 16       // rank slices
#define SLICE 512   // NBOX / NS
#define NBLK 32     // rank blocks per slice
#define TAILB 81    // tail kernel grid (80 classes + 1 hazard check)

// ---- monotone float<->uint mapping (order-preserving for all floats) ----
__device__ __forceinline__ u32 f32_mono(float f) {
  u32 u = __float_as_uint(f);
  return (u & 0x80000000u) ? ~u : (u | 0x80000000u);
}
__device__ __forceinline__ float mono_f32(u32 u) {
  u32 b = (u & 0x80000000u) ? (u ^ 0x80000000u) : ~u;
  return __uint_as_float(b);
}
__device__ __forceinline__ float readlane_f(float v, int l) {
  return __uint_as_float(__builtin_amdgcn_readlane(__float_as_uint(v), l));
}
// reduce 32-entry u32 array of block maxima, in-register
__device__ __forceinline__ u32 reduce_bmax(const u32* __restrict__ bmax, int t) {
  u32 bm = bmax[t & 31];
#pragma unroll
  for (int off = 16; off > 0; off >>= 1) {
    u32 o = __shfl_xor(bm, off);
    bm = (bm > o) ? bm : o;
  }
  return bm;
}

// ---- grid barrier for TAILB co-resident blocks. Arrival = one device-scope
// RMW per block; polling = RELAXED AGENT *loads* (no RMW convoy — r7 lesson:
// atomicAdd(p,0) polling from all blocks serialized the coherence point and
// cost ~80us). threadfence before/after gives release/acquire for plain
// stores across XCD L2s.
__device__ __forceinline__ void gbar(u32* bar) {
  __syncthreads();
  if (threadIdx.x == 0) {
    __threadfence();  // release
    u32 ticket = __hip_atomic_fetch_add(bar, 1u, __ATOMIC_ACQ_REL,
                                        __HIP_MEMORY_SCOPE_AGENT);
    u32 target = (ticket / TAILB) * TAILB + TAILB;
    while (__hip_atomic_load(bar, __ATOMIC_RELAXED, __HIP_MEMORY_SCOPE_AGENT) <
           target) {
      __builtin_amdgcn_s_sleep(8);
    }
    __threadfence();  // acquire
  }
  __syncthreads();
}

// ---- K1: rank-by-enumeration + box decode/block-max (slice 0) + ws init.
// Rank key: (~mono(score) << 32) | (idx << 8) | cls.
__global__ __launch_bounds__(256) void rank_decode_kernel(
    const float* __restrict__ scores, const int* __restrict__ class_ids,
    const float4* __restrict__ deltas, const float2* __restrict__ locs,
    const int* __restrict__ stride_p, float4* __restrict__ boxes_out,
    u32* __restrict__ bmax, int* __restrict__ flag, int* __restrict__ ccount,
    u32* __restrict__ bar, int* __restrict__ rankp, int* __restrict__ rcp) {
  int t = threadIdx.x;
  int i = blockIdx.x * 256 + t;
  int slice = blockIdx.y;

  __shared__ u64 kt[SLICE];
  __shared__ u32 wmax[4];

  if (slice == 0) {  // decode boxes + block max + ws init (block-uniform)
    float s = (float)(*stride_p);
    float4 d = deltas[i];
    d.x = fmaxf(d.x, 0.f); d.y = fmaxf(d.y, 0.f);
    d.z = fmaxf(d.z, 0.f); d.w = fmaxf(d.w, 0.f);
    float2 c = locs[i];
    float4 b;
    b.x = c.x - s * d.x;
    b.y = c.y - s * d.y;
    b.z = c.x + s * d.z;
    b.w = c.y + s * d.w;
    boxes_out[i] = b;
    float m = fmaxf(fmaxf(b.x, b.y), fmaxf(b.z, b.w));
    u32 u = f32_mono(m);
#pragma unroll
    for (int off = 32; off > 0; off >>= 1) {
      u32 o = __shfl_xor(u, off);
      u = (u > o) ? u : o;
    }
    if ((t & 63) == 0) wmax[t >> 6] = u;
    __syncthreads();
    if (t == 0) {
      u32 m0 = wmax[0] > wmax[1] ? wmax[0] : wmax[1];
      u32 m1 = wmax[2] > wmax[3] ? wmax[2] : wmax[3];
      bmax[blockIdx.x] = m0 > m1 ? m0 : m1;  // plain store
    }
    if (blockIdx.x == 0) {  // init for K2 (kernel-boundary coherence)
      if (t == 0) { *flag = 0; *bar = 0; }
      if (t < NCLASS) ccount[t] = 0;
    }
  }

  for (int p = t; p < SLICE; p += 256) {
    int j = slice * SLICE + p;
    u32 mj = f32_mono(scores[j]);
    kt[p] = ((u64)(~mj) << 32) | ((u32)j << 8) | (u32)(class_ids[j] & 0xff);
  }
  __syncthreads();

  u32 mi = f32_mono(scores[i]);
  u32 ci = (u32)(class_ids[i] & 0xff);
  u64 ki = ((u64)(~mi) << 32) | ((u32)i << 8) | ci;
  int cnt = 0, ccnt = 0;
#pragma unroll 8
  for (int p = 0; p < SLICE; ++p) {
    u64 kj = kt[p];  // wave-uniform LDS address -> broadcast
    bool less = kj < ki;
    bool ceq = (((u32)(kj ^ ki)) & 0xffu) == 0u;
    cnt += less ? 1 : 0;
    ccnt += (less && ceq) ? 1 : 0;
  }
  rankp[slice * NBOX + i] = cnt;
  rcp[slice * NBOX + i] = ccnt;
}

// ---- K2: fused tail. Blocks 0..31 scatter; barrier; blocks 0..79 register
// NMS + block 80 hazard check; barrier; block 0 flag-guarded exact fallback.
// No early returns (all blocks reach both gbar calls).
__global__ __launch_bounds__(256) void tail_kernel(
    const float* __restrict__ scores, const int* __restrict__ class_ids,
    const float4* __restrict__ boxes, const u32* __restrict__ bmax,
    const int* __restrict__ rankp, const int* __restrict__ rcp,
    u64* __restrict__ keys, float4* __restrict__ bnms,
    u32* __restrict__ clist, int* __restrict__ ccount,
    float* __restrict__ order_out, float* __restrict__ keep_out,
    int* flag, u32* bar) {
  const int t = threadIdx.x;
  const int bid = blockIdx.x;

  __shared__ float4 bxA[CHKCAP], bxB[CHKCAP];
  __shared__ int clsA[CHKCAP], clsB[CHKCAP];
  __shared__ int na, nb;
  __shared__ u64 remv[NW64];

  // ---------------- phase C: scatter by rank (blocks 0..31) ----------------
  if (bid < NBLK) {
    int i = bid * 256 + t;
    int r = 0, rc = 0;
#pragma unroll
    for (int s = 0; s < NS; ++s) {
      r += rankp[s * NBOX + i];
      rc += rcp[s * NBOX + i];
    }
    float maxc = mono_f32(reduce_bmax(bmax, t));
    u32 mi = f32_mono(scores[i]);
    keys[r] = ((u64)(~mi) << 32) | (u32)i;  // clean key for fallback
    int cls = class_ids[i];
    float off = (float)cls * (maxc + 1.0f);
    float4 b = boxes[i];
    b.x += off; b.y += off; b.z += off; b.w += off;
    bnms[r] = b;
    order_out[r] = (float)i;
    if (rc < MAXC)
      clist[cls * MAXC + rc] = ((u32)i << 16) | (u32)r;
    else
      atomicOr(flag, 1);  // class overflow -> exact fallback
    atomicAdd(&ccount[cls], 1);
  }

  gbar(bar);

  // ---------- phase E: per-class NMS (0..79) + hazard check (80) -----------
  if (bid == NCLASS) {
    // Cross-class hazard: adjacent-class offset boxes can only overlap if one
    // box hugs the top-right margin (x2,y2 > M-65; x1,y1 >= -64 by
    // construction) and the other the bottom-left margin (x1,y1 < 1).
    // Conservative IoU > 0.4 vs reference 0.5.
    if (t == 0) { na = 0; nb = 0; }
    __syncthreads();
    float M = mono_f32(reduce_bmax(bmax, t));
    float thrA = M - 65.0f;
    for (int base = 0; base < NBOX; base += 256) {
      int ii = base + t;
      float4 bb = boxes[ii];
      int cls = class_ids[ii];
      if (bb.z > thrA && bb.w > thrA) {
        int p = atomicAdd(&na, 1);
        if (p < CHKCAP) { bxA[p] = bb; clsA[p] = cls; }
      }
      if (bb.x < 1.0f && bb.y < 1.0f) {
        int p = atomicAdd(&nb, 1);
        if (p < CHKCAP) { bxB[p] = bb; clsB[p] = cls; }
      }
    }
    __syncthreads();
    int NA = na < CHKCAP ? na : CHKCAP;
    int NB = nb < CHKCAP ? nb : CHKCAP;
    if (t == 0 && (na > CHKCAP || nb > CHKCAP)) atomicOr(flag, 1);
    bool hit = false;
    for (int pr = t; pr < NA * NB; pr += 256) {
      int a = pr / NB, b2 = pr % NB;
      if (clsB[b2] != clsA[a] + 1) continue;
      float offa = (float)clsA[a] * (M + 1.0f);
      float offb = (float)clsB[b2] * (M + 1.0f);
      float4 A = bxA[a], Bb = bxB[b2];
      A.x += offa; A.y += offa; A.z += offa; A.w += offa;
      Bb.x += offb; Bb.y += offb; Bb.z += offb; Bb.w += offb;
      float ltx = fmaxf(A.x, Bb.x), lty = fmaxf(A.y, Bb.y);
      float rbx = fminf(A.z, Bb.z), rby = fminf(A.w, Bb.w);
      float ww = fmaxf(rbx - ltx, 0.f), hh = fmaxf(rby - lty, 0.f);
      float inter = ww * hh;
      float aa = (A.z - A.x) * (A.w - A.y);
      float ab = (Bb.z - Bb.x) * (Bb.w - Bb.y);
      float iou = inter / (aa + ab - inter);
      if (iou > 0.4f) hit = true;
    }
    if (hit) atomicOr(flag, 1);
  } else if (t < 64) {
    // all-register greedy NMS: lane t owns boxes t, t+64, t+128, t+192 of
    // class `bid`; remv = 4 wave-uniform u64 (SGPR). Per kept row i:
    // 4 readlanes broadcast box i, <=4 IoU+ballot passes. No LDS.
    int c = bid;
    int nc = ccount[c];
    if (nc > NCMAX) {
      if (t == 0) atomicOr(flag, 1);
    } else {
      u32 L[4];
      float4 B[4];
#pragma unroll
      for (int d = 0; d < 4; ++d) {
        int j = d * 64 + t;
        L[d] = (j < nc) ? clist[c * MAXC + j] : 0u;
        B[d] = bnms[L[d] & 0xffffu];  // j>=nc -> harmless read of bnms[0]
      }
      u64 r0 = 0, r1 = 0, r2 = 0, r3 = 0;

#define CHUNK(CC, RC, PASSES)                                                  \
  {                                                                            \
    int lim = nc - CC * 64;                                                    \
    if (lim > 0) {                                                             \
      if (lim > 64) lim = 64;                                                  \
      for (int ii = 0; ii < lim; ++ii) {                                       \
        if (!((RC >> ii) & 1ull)) {                                            \
          float bix = readlane_f(B[CC].x, ii);                                 \
          float biy = readlane_f(B[CC].y, ii);                                 \
          float biz = readlane_f(B[CC].z, ii);                                 \
          float biw = readlane_f(B[CC].w, ii);                                 \
          float area_i = (biz - bix) * (biw - biy);                            \
          PASSES                                                               \
        }                                                                      \
      }                                                                        \
    }                                                                          \
  }
#define PASS(DD, RD, JGUARD)                                                   \
  {                                                                            \
    float4 bj = B[DD];                                                         \
    float ltx = fmaxf(bix, bj.x), lty = fmaxf(biy, bj.y);                      \
    float rbx = fminf(biz, bj.z), rby = fminf(biw, bj.w);                      \
    float ww = fmaxf(rbx - ltx, 0.f), hh = fmaxf(rby - lty, 0.f);              \
    float inter = ww * hh;                                                     \
    float area_j = (bj.z - bj.x) * (bj.w - bj.y);                              \
    float iou = inter / (area_i + area_j - inter);                             \
    int j = DD * 64 + t;                                                       \
    bool p = (iou > 0.5f) && (j < nc) && (JGUARD);                             \
    RD |= __ballot(p);                                                         \
  }

      CHUNK(0, r0, PASS(0, r0, t > ii) PASS(1, r1, true) PASS(2, r2, true) PASS(3, r3, true))
      CHUNK(1, r1, PASS(1, r1, t > ii) PASS(2, r2, true) PASS(3, r3, true))
      CHUNK(2, r2, PASS(2, r2, t > ii) PASS(3, r3, true))
      CHUNK(3, r3, PASS(3, r3, t > ii))
#undef PASS
#undef CHUNK

      u64 rr[4] = {r0, r1, r2, r3};
#pragma unroll
      for (int d = 0; d < 4; ++d) {
        int j = d * 64 + t;
        if (j < nc) keep_out[L[d] >> 16] = ((rr[d] >> t) & 1ull) ? 0.0f : 1.0f;
      }
    }
  }

  gbar(bar);

  // ------- phase G: exact single-block fallback (only if flag != 0) --------
  if (bid == 0 && *flag != 0) {
    for (int k = t; k < NW64; k += 256) remv[k] = 0;
    __syncthreads();
    if (t < 64) {
      int lane = t;
      for (int ii = 0; ii < NBOX; ++ii) {
        if ((remv[ii >> 6] >> (ii & 63)) & 1ull) continue;
        float4 bi = bnms[ii];
        float area_i = (bi.z - bi.x) * (bi.w - bi.y);
        for (int jb = ii + 1; jb < NBOX; jb += 64) {
          int j = jb + lane;
          bool p = false;
          if (j < NBOX) {
            float4 bj = bnms[j];
            float ltx = fmaxf(bi.x, bj.x), lty = fmaxf(bi.y, bj.y);
            float rbx = fminf(bi.z, bj.z), rby = fminf(bi.w, bj.w);
            float ww = fmaxf(rbx - ltx, 0.f), hh = fmaxf(rby - lty, 0.f);
            float inter = ww * hh;
            float area_j = (bj.z - bj.x) * (bj.w - bj.y);
            float iou = inter / (area_i + area_j - inter);
            p = iou > 0.5f;
          }
          u64 m = __ballot(p);
          if (lane == 0 && m) {
            int w0 = jb >> 6, sh = jb & 63;
            remv[w0] |= (m << sh);
            if (sh && (w0 + 1) < NW64) remv[w0 + 1] |= (m >> (64 - sh));
          }
        }
      }
    }
    __syncthreads();
    for (int k = t; k < NBOX; k += 256)
      keep_out[(u32)keys[k]] = ((remv[k >> 6] >> (k & 63)) & 1ull) ? 0.0f : 1.0f;
  }
}

extern "C" void kernel_launch(void* const* d_in, const int* in_sizes, int n_in,
                              void* d_out, int out_size, void* d_ws, size_t ws_size,
                              hipStream_t stream) {
  const float* deltas = (const float*)d_in[0];
  const float* locs = (const float*)d_in[1];
  const float* scores = (const float*)d_in[2];
  const int* class_ids = (const int*)d_in[3];
  const int* stride_p = (const int*)d_in[4];

  float* boxes_out = (float*)d_out;                     // n*4 floats
  float* keep_out = (float*)d_out + (size_t)NBOX * 4;   // n floats (0/1)
  float* order_out = (float*)d_out + (size_t)NBOX * 5;  // n floats (indices)

  // workspace layout (all init done in-kernel; no memset nodes)
  u32* bar = (u32*)d_ws;                          // barrier ticket
  u32* bmax = (u32*)((char*)d_ws + 64);           // 32*4 B, plain-stored
  int* flag = (int*)((char*)d_ws + 256);          // init'd by K1
  int* ccount = (int*)((char*)d_ws + 512);        // 80*4 B, init'd by K1
  u64* keys = (u64*)((char*)d_ws + 4096);         // 64 KiB
  float4* bnms = (float4*)((char*)d_ws + 4096 + 65536);  // 128 KiB
  char* base2 = (char*)d_ws + 4096 + 65536 + 131072;
  int* rankp = (int*)base2;                       // NS*8192*4 = 512 KiB
  int* rcp = (int*)(base2 + 512 * 1024);          // 512 KiB
  u32* clist = (u32*)(base2 + 1024 * 1024);       // 80*512*4 = 160 KiB

  rank_decode_kernel<<<dim3(NBLK, NS), 256, 0, stream>>>(
      scores, class_ids, (const float4*)deltas, (const float2*)locs, stride_p,
      (float4*)boxes_out, bmax, flag, ccount, bar, rankp, rcp);

  tail_kernel<<<TAILB, 256, 0, stream>>>(
      scores, class_ids, (const float4*)boxes_out, bmax, rankp, rcp, keys,
      bnms, clist, ccount, order_out, keep_out, flag, bar);
}